// Round 1
// baseline (246.410 us; speedup 1.0000x reference)
//
#include <hip/hip_runtime.h>
#include <hip/hip_bf16.h>

// RelationsNetwork on MI355X.
// Decomposition: h1 = relu(u[j] + v[i] + (x_i*x_j)@W_c + b1), u=x@W_a, v=x@W_b
// where g_w1 = [W_a; W_b; W_c] (rows 0:258, 258:516, 516:774).
// Main kernel: one block per (b,i); fused 3-layer MFMA GEMM chain in LDS;
// j-reduction in-register; atomicAdd into rel[b,h]. K padded 258->288.

typedef __attribute__((ext_vector_type(4))) float f32x4;
typedef __attribute__((ext_vector_type(8))) short frag8;  // 8 bf16 = 4 VGPR
typedef __attribute__((ext_vector_type(4))) short s4;     // 8 bytes

__device__ __forceinline__ float bf2f(short s) {
  return __uint_as_float(((unsigned)(unsigned short)s) << 16);
}
__device__ __forceinline__ short f2bf(float f) {
  unsigned u = __float_as_uint(f);
  return (short)((u + 0x7fffu + ((u >> 16) & 1u)) >> 16);
}

#define B_SZ 32
#define S_SZ 64
#define DM 256
#define KX 288   // padded 258 -> 288 (mult of 32)
#define H_SZ 256

// ---------------- small prep kernels ----------------

// xb[(b*64+s)*288 + k] = bf16(x[b,s,k]); k<256 sentences, 256..257 coord, else 0
__global__ void build_x(const float* __restrict__ sent, const float* __restrict__ coord,
                        short* __restrict__ xb) {
  int idx = blockIdx.x * 256 + threadIdx.x;
  if (idx >= 2048 * KX) return;
  int row = idx / KX, k = idx - row * KX;
  float v = 0.f;
  if (k < 256)      v = sent[row * 256 + k];
  else if (k < 258) v = coord[row * 2 + (k - 256)];
  xb[idx] = f2bf(v);
}

// Wab_t[n][k], n in [0,512): n<256 -> W_a col n; n>=256 -> W_b col n-256. K padded.
__global__ void build_wab(const float* __restrict__ g_w1, short* __restrict__ Wab) {
  int idx = blockIdx.x * 256 + threadIdx.x;
  if (idx >= 512 * KX) return;
  int n = idx / KX, k = idx - n * KX;
  float v = 0.f;
  if (k < 258) {
    int row = (n < 256) ? k : (258 + k);
    int col = (n < 256) ? n : (n - 256);
    v = g_w1[row * 256 + col];
  }
  Wab[idx] = f2bf(v);
}

// Wc_t[n][k] = g_w1[516+k][n], K padded
__global__ void build_wc(const float* __restrict__ g_w1, short* __restrict__ Wc) {
  int idx = blockIdx.x * 256 + threadIdx.x;
  if (idx >= 256 * KX) return;
  int n = idx / KX, k = idx - n * KX;
  float v = (k < 258) ? g_w1[(516 + k) * 256 + n] : 0.f;
  Wc[idx] = f2bf(v);
}

// transpose 256x256 fp32 -> bf16 [n][k]
__global__ void build_wt(const float* __restrict__ W, short* __restrict__ Wt) {
  int idx = blockIdx.x * 256 + threadIdx.x;
  if (idx >= 256 * 256) return;
  int n = idx >> 8, k = idx & 255;
  Wt[idx] = f2bf(W[k * 256 + n]);
}

// ---------------- u/v GEMM: uv[m][0:256]=x@W_a, uv[m][256:512]=x@W_b + b1 ----------------

__global__ __launch_bounds__(256)
void uv_gemm(const short* __restrict__ xb, const short* __restrict__ Wab,
             const float* __restrict__ g_b1, float* __restrict__ uv) {
  const int m0 = blockIdx.x * 64;
  const int lane = threadIdx.x & 63, wave = threadIdx.x >> 6;
  const int q = lane >> 4, l16 = lane & 15;
  const int n0 = blockIdx.y * 256 + wave * 64;

  f32x4 acc[4][4];
#pragma unroll
  for (int mt = 0; mt < 4; mt++)
#pragma unroll
    for (int nt = 0; nt < 4; nt++) acc[mt][nt] = (f32x4){0.f, 0.f, 0.f, 0.f};

  for (int k0 = 0; k0 < KX; k0 += 32) {
    frag8 a[4], bb[4];
#pragma unroll
    for (int mt = 0; mt < 4; mt++)
      a[mt] = *(const frag8*)(xb + (size_t)(m0 + mt * 16 + l16) * KX + k0 + q * 8);
#pragma unroll
    for (int nt = 0; nt < 4; nt++)
      bb[nt] = *(const frag8*)(Wab + (size_t)(n0 + nt * 16 + l16) * KX + k0 + q * 8);
#pragma unroll
    for (int mt = 0; mt < 4; mt++)
#pragma unroll
      for (int nt = 0; nt < 4; nt++)
        acc[mt][nt] = __builtin_amdgcn_mfma_f32_16x16x32_bf16(a[mt], bb[nt], acc[mt][nt], 0, 0, 0);
  }
#pragma unroll
  for (int nt = 0; nt < 4; nt++) {
    int col = n0 + nt * 16 + l16;
    float bias = (col >= 256) ? g_b1[col - 256] : 0.f;
#pragma unroll
    for (int mt = 0; mt < 4; mt++) {
      int m = m0 + mt * 16 + q * 4;
#pragma unroll
      for (int r = 0; r < 4; r++)
        uv[(size_t)(m + r) * 512 + col] = acc[mt][nt][r] + bias;
    }
  }
}

// ---------------- main fused relation kernel ----------------
// block = (b, i). LDS: ldsA holds pair-product A1 chunks (k:192 then 96),
// ldsH holds h1 then h2 (layer-2 output lives in regs across the swap barrier).

#define AS1 200   // stride for 192-elem chunk (400B row = 25*16, bank period 8)
#define AS2 104   // stride for 96-elem chunk  (208B row = 13*16, bank period 8)
#define HS 264    // h stride (528B row = 33*16, bank period 8)

__global__ __launch_bounds__(256, 2)
void relnet_main(const short* __restrict__ xb, const short* __restrict__ Wc,
                 const short* __restrict__ W2t, const short* __restrict__ W3t,
                 const float* __restrict__ uv, const float* __restrict__ g_b2,
                 const float* __restrict__ g_b3, float* __restrict__ rel) {
  __shared__ short ldsA[64 * AS1];   // 25600 B
  __shared__ short ldsH[64 * HS];    // 33792 B   (total 59392 < 64K)

  const int tid = threadIdx.x;
  const int bi = blockIdx.x;
  const int b = bi >> 6, i = bi & 63;
  const int lane = tid & 63, wave = tid >> 6;
  const int q = lane >> 4, l16 = lane & 15;
  const int n0 = wave * 64;
  const int rowbase = b * 64;
  const short* xi = xb + (size_t)(rowbase + i) * KX;

  f32x4 acc[4][4];
#pragma unroll
  for (int mt = 0; mt < 4; mt++)
#pragma unroll
    for (int nt = 0; nt < 4; nt++) acc[mt][nt] = (f32x4){0.f, 0.f, 0.f, 0.f};

  // ---- layer 1, chunk 1: k in [0,192) ----
  for (int idx = tid; idx < 64 * 48; idx += 256) {
    int j = idx / 48, k4 = (idx - j * 48) * 4;
    s4 aj = *(const s4*)(xb + (size_t)(rowbase + j) * KX + k4);
    s4 ai = *(const s4*)(xi + k4);
    s4 r;
#pragma unroll
    for (int t = 0; t < 4; t++) r[t] = f2bf(bf2f(aj[t]) * bf2f(ai[t]));
    *(s4*)(&ldsA[j * AS1 + k4]) = r;
  }
  __syncthreads();
  for (int k0 = 0; k0 < 192; k0 += 32) {
    frag8 a[4], bb[4];
#pragma unroll
    for (int mt = 0; mt < 4; mt++)
      a[mt] = *(const frag8*)(&ldsA[(mt * 16 + l16) * AS1 + k0 + q * 8]);
#pragma unroll
    for (int nt = 0; nt < 4; nt++)
      bb[nt] = *(const frag8*)(Wc + (size_t)(n0 + nt * 16 + l16) * KX + k0 + q * 8);
#pragma unroll
    for (int mt = 0; mt < 4; mt++)
#pragma unroll
      for (int nt = 0; nt < 4; nt++)
        acc[mt][nt] = __builtin_amdgcn_mfma_f32_16x16x32_bf16(a[mt], bb[nt], acc[mt][nt], 0, 0, 0);
  }
  __syncthreads();
  // ---- layer 1, chunk 2: k in [192,288) ----
  for (int idx = tid; idx < 64 * 24; idx += 256) {
    int j = idx / 24, k4 = (idx - j * 24) * 4;
    s4 aj = *(const s4*)(xb + (size_t)(rowbase + j) * KX + 192 + k4);
    s4 ai = *(const s4*)(xi + 192 + k4);
    s4 r;
#pragma unroll
    for (int t = 0; t < 4; t++) r[t] = f2bf(bf2f(aj[t]) * bf2f(ai[t]));
    *(s4*)(&ldsA[j * AS2 + k4]) = r;
  }
  __syncthreads();
  for (int k0 = 0; k0 < 96; k0 += 32) {
    frag8 a[4], bb[4];
#pragma unroll
    for (int mt = 0; mt < 4; mt++)
      a[mt] = *(const frag8*)(&ldsA[(mt * 16 + l16) * AS2 + k0 + q * 8]);
#pragma unroll
    for (int nt = 0; nt < 4; nt++)
      bb[nt] = *(const frag8*)(Wc + (size_t)(n0 + nt * 16 + l16) * KX + 192 + k0 + q * 8);
#pragma unroll
    for (int mt = 0; mt < 4; mt++)
#pragma unroll
      for (int nt = 0; nt < 4; nt++)
        acc[mt][nt] = __builtin_amdgcn_mfma_f32_16x16x32_bf16(a[mt], bb[nt], acc[mt][nt], 0, 0, 0);
  }

  // ---- layer 1 epilogue: h1 = relu(acc + u[j] + v[i] + b1) -> ldsH (bf16) ----
  {
    const float* ub = uv + (size_t)rowbase * 512;
    const float* vp = uv + (size_t)(rowbase + i) * 512 + 256;  // v + b1 already
#pragma unroll
    for (int nt = 0; nt < 4; nt++) {
      int col = n0 + nt * 16 + l16;
      float vv = vp[col];
#pragma unroll
      for (int mt = 0; mt < 4; mt++) {
        int jb = mt * 16 + q * 4;
#pragma unroll
        for (int r = 0; r < 4; r++) {
          float val = acc[mt][nt][r] + ub[(size_t)(jb + r) * 512 + col] + vv;
          ldsH[(jb + r) * HS + col] = f2bf(fmaxf(val, 0.f));
        }
        acc[mt][nt] = (f32x4){0.f, 0.f, 0.f, 0.f};
      }
    }
  }
  __syncthreads();

  // ---- layer 2: h2 = relu(h1 @ W2 + b2) ----
  for (int k0 = 0; k0 < 256; k0 += 32) {
    frag8 a[4], bb[4];
#pragma unroll
    for (int mt = 0; mt < 4; mt++)
      a[mt] = *(const frag8*)(&ldsH[(mt * 16 + l16) * HS + k0 + q * 8]);
#pragma unroll
    for (int nt = 0; nt < 4; nt++)
      bb[nt] = *(const frag8*)(W2t + (size_t)(n0 + nt * 16 + l16) * 256 + k0 + q * 8);
#pragma unroll
    for (int mt = 0; mt < 4; mt++)
#pragma unroll
      for (int nt = 0; nt < 4; nt++)
        acc[mt][nt] = __builtin_amdgcn_mfma_f32_16x16x32_bf16(a[mt], bb[nt], acc[mt][nt], 0, 0, 0);
  }
  __syncthreads();  // all waves done READING h1 before overwriting with h2
#pragma unroll
  for (int nt = 0; nt < 4; nt++) {
    int col = n0 + nt * 16 + l16;
    float b2 = g_b2[col];
#pragma unroll
    for (int mt = 0; mt < 4; mt++) {
      int jb = mt * 16 + q * 4;
#pragma unroll
      for (int r = 0; r < 4; r++)
        ldsH[(jb + r) * HS + col] = f2bf(fmaxf(acc[mt][nt][r] + b2, 0.f));
      acc[mt][nt] = (f32x4){0.f, 0.f, 0.f, 0.f};
    }
  }
  __syncthreads();

  // ---- layer 3: h3 = relu(h2 @ W3 + b3), reduce over j, atomic into rel ----
  for (int k0 = 0; k0 < 256; k0 += 32) {
    frag8 a[4], bb[4];
#pragma unroll
    for (int mt = 0; mt < 4; mt++)
      a[mt] = *(const frag8*)(&ldsH[(mt * 16 + l16) * HS + k0 + q * 8]);
#pragma unroll
    for (int nt = 0; nt < 4; nt++)
      bb[nt] = *(const frag8*)(W3t + (size_t)(n0 + nt * 16 + l16) * 256 + k0 + q * 8);
#pragma unroll
    for (int mt = 0; mt < 4; mt++)
#pragma unroll
      for (int nt = 0; nt < 4; nt++)
        acc[mt][nt] = __builtin_amdgcn_mfma_f32_16x16x32_bf16(a[mt], bb[nt], acc[mt][nt], 0, 0, 0);
  }
#pragma unroll
  for (int nt = 0; nt < 4; nt++) {
    int col = n0 + nt * 16 + l16;
    float b3 = g_b3[col];
    float s = 0.f;
#pragma unroll
    for (int mt = 0; mt < 4; mt++)
#pragma unroll
      for (int r = 0; r < 4; r++)
        s += fmaxf(acc[mt][nt][r] + b3, 0.f);
    s += __shfl_xor(s, 16, 64);
    s += __shfl_xor(s, 32, 64);
    if (q == 0) atomicAdd(&rel[b * 256 + col], s);
  }
}

// ---------------- f-network (fp32, exact) ----------------
__global__ __launch_bounds__(256)
void fnet(const float* __restrict__ rel, const float* __restrict__ f_w1,
          const float* __restrict__ f_b1, const float* __restrict__ f_w2,
          const float* __restrict__ f_b2, const float* __restrict__ f_w3,
          const float* __restrict__ f_b3, float* __restrict__ out) {
  int b = blockIdx.x, t = threadIdx.x;
  __shared__ float y0[256], y1[256], y2[256];
  y0[t] = rel[b * 256 + t];
  __syncthreads();
  float s = f_b1[t];
#pragma unroll 8
  for (int k = 0; k < 256; k++) s += y0[k] * f_w1[k * 256 + t];
  y1[t] = fmaxf(s, 0.f);
  __syncthreads();
  s = f_b2[t];
#pragma unroll 8
  for (int k = 0; k < 256; k++) s += y1[k] * f_w2[k * 256 + t];
  y2[t] = fmaxf(s, 0.f);
  __syncthreads();
  if (t < 10) {
    float s2 = f_b3[t];
#pragma unroll 8
    for (int k = 0; k < 256; k++) s2 += y2[k] * f_w3[k * 10 + t];
    out[b * 10 + t] = s2;
  }
}

// ---------------- launch ----------------
extern "C" void kernel_launch(void* const* d_in, const int* in_sizes, int n_in,
                              void* d_out, int out_size, void* d_ws, size_t ws_size,
                              hipStream_t stream) {
  const float* sent  = (const float*)d_in[0];
  const float* coord = (const float*)d_in[1];
  const float* g_w1  = (const float*)d_in[2];
  const float* g_b1  = (const float*)d_in[3];
  const float* g_w2  = (const float*)d_in[4];
  const float* g_b2  = (const float*)d_in[5];
  const float* g_w3  = (const float*)d_in[6];
  const float* g_b3  = (const float*)d_in[7];
  const float* f_w1  = (const float*)d_in[8];
  const float* f_b1  = (const float*)d_in[9];
  const float* f_w2  = (const float*)d_in[10];
  const float* f_b2  = (const float*)d_in[11];
  const float* f_w3  = (const float*)d_in[12];
  const float* f_b3  = (const float*)d_in[13];
  float* out = (float*)d_out;

  char* ws = (char*)d_ws;
  size_t off = 0;
  auto alloc = [&](size_t bytes) {
    char* p = ws + off;
    off += (bytes + 255) & ~(size_t)255;
    return p;
  };
  short* xb  = (short*)alloc((size_t)2048 * KX * 2);
  short* Wab = (short*)alloc((size_t)512 * KX * 2);
  short* Wc  = (short*)alloc((size_t)256 * KX * 2);
  short* W2t = (short*)alloc((size_t)256 * 256 * 2);
  short* W3t = (short*)alloc((size_t)256 * 256 * 2);
  float* uv  = (float*)alloc((size_t)2048 * 512 * 4);
  float* rel = (float*)alloc((size_t)32 * 256 * 4);

  hipMemsetAsync(rel, 0, 32 * 256 * 4, stream);
  build_x<<<(2048 * KX + 255) / 256, 256, 0, stream>>>(sent, coord, xb);
  build_wab<<<(512 * KX + 255) / 256, 256, 0, stream>>>(g_w1, Wab);
  build_wc<<<(256 * KX + 255) / 256, 256, 0, stream>>>(g_w1, Wc);
  build_wt<<<(256 * 256 + 255) / 256, 256, 0, stream>>>(g_w2, W2t);
  build_wt<<<(256 * 256 + 255) / 256, 256, 0, stream>>>(g_w3, W3t);
  uv_gemm<<<dim3(32, 2), 256, 0, stream>>>(xb, Wab, g_b1, uv);
  relnet_main<<<2048, 256, 0, stream>>>(xb, Wc, W2t, W3t, uv, g_b2, g_b3, rel);
  fnet<<<32, 256, 0, stream>>>(rel, f_w1, f_b1, f_w2, f_b2, f_w3, f_b3, out);
}

// Round 2
// 231.450 us; speedup vs baseline: 1.0646x; 1.0646x over previous
//
#include <hip/hip_runtime.h>
#include <hip/hip_bf16.h>

// RelationsNetwork on MI355X.
// Decomposition: h1 = relu(u[j] + v[i] + (x_i*x_j)@W_c + b1), u=x@W_a, v=x@W_b
// where g_w1 = [W_a; W_b; W_c] (rows 0:258, 258:516, 516:774).
// Main kernel: one block per (b,i); fused 3-layer MFMA GEMM chain in LDS;
// A-products and H buffers ALIASED in one LDS union (38912 B -> 4 blocks/CU,
// round-1 had 59392 B -> 2 blocks/CU, occupancy 22% and latency-bound).
// j-reduction in-register; atomicAdd into rel[b,h]. K padded 258->288.

typedef __attribute__((ext_vector_type(4))) float f32x4;
typedef __attribute__((ext_vector_type(8))) short frag8;  // 8 bf16 = 4 VGPR
typedef __attribute__((ext_vector_type(4))) short s4;     // 8 bytes

__device__ __forceinline__ float bf2f(short s) {
  return __uint_as_float(((unsigned)(unsigned short)s) << 16);
}
__device__ __forceinline__ short f2bf(float f) {
  unsigned u = __float_as_uint(f);
  return (short)((u + 0x7fffu + ((u >> 16) & 1u)) >> 16);
}

#define KX 288   // padded 258 -> 288 (mult of 32)

// ---------------- merged prep kernel ----------------
// regions by blockIdx.x:
//   [0,288)    build_x:  xb[(b*64+s)*288+k] = bf16(x[b,s,k])
//   [288,328)  Wab:  [n][k] n<256 -> W_a col n ; n>=256 -> W_b col n-256
//   [328,348)  Wc:   [n][k] = g_w1[516+k][n]
//   [348,364)  W2t:  [n][k] = g_w2[k][n]
//   [364,380)  W3t:  [n][k] = g_w3[k][n]
//   [380,388)  zero rel
__global__ __launch_bounds__(256)
void prep(const float* __restrict__ sent, const float* __restrict__ coord,
          const float* __restrict__ g_w1, const float* __restrict__ g_w2,
          const float* __restrict__ g_w3,
          short* __restrict__ xb, short* __restrict__ Wab, short* __restrict__ Wc,
          short* __restrict__ W2t, short* __restrict__ W3t, float* __restrict__ rel) {
  __shared__ short tile[64 * 66];  // odd-dword stride: conflict-free transpose
  const int blk = blockIdx.x, t = threadIdx.x;

  if (blk < 288) {
    long idx0 = ((long)blk * 256 + t) * 8;
#pragma unroll
    for (int e = 0; e < 8; e++) {
      long idx = idx0 + e;
      int row = (int)(idx / KX), k = (int)(idx - (long)row * KX);
      float v = 0.f;
      if (k < 256)      v = sent[(size_t)row * 256 + k];
      else if (k < 258) v = coord[row * 2 + (k - 256)];
      xb[idx] = f2bf(v);
    }
    return;
  }

  const int nc = t & 63, r4 = t >> 6;  // read: 4 rows x 64 cols per pass
  if (blk < 328) {  // Wab
    int tt = blk - 288, kt = tt >> 3, nt = tt & 7;
    int k0 = kt * 64, n0 = nt * 64;
    for (int p = 0; p < 16; p++) {
      int kl = p * 4 + r4, k = k0 + kl, n = n0 + nc;
      float v = 0.f;
      if (k < 258) {
        int row = (n < 256) ? k : 258 + k;
        int col = (n < 256) ? n : n - 256;
        v = g_w1[(size_t)row * 256 + col];
      }
      tile[kl * 66 + nc] = f2bf(v);
    }
    __syncthreads();
    for (int p = 0; p < 16; p++) {
      int nl = p * 4 + r4;
      if (k0 + nc < KX) Wab[(size_t)(n0 + nl) * KX + k0 + nc] = tile[nc * 66 + nl];
    }
    return;
  }
  if (blk < 348) {  // Wc
    int tt = blk - 328, kt = tt >> 2, nt = tt & 3;
    int k0 = kt * 64, n0 = nt * 64;
    for (int p = 0; p < 16; p++) {
      int kl = p * 4 + r4, k = k0 + kl;
      float v = (k < 258) ? g_w1[(size_t)(516 + k) * 256 + n0 + nc] : 0.f;
      tile[kl * 66 + nc] = f2bf(v);
    }
    __syncthreads();
    for (int p = 0; p < 16; p++) {
      int nl = p * 4 + r4;
      if (k0 + nc < KX) Wc[(size_t)(n0 + nl) * KX + k0 + nc] = tile[nc * 66 + nl];
    }
    return;
  }
  if (blk < 380) {  // W2t / W3t
    int tt = blk - 348;
    const float* W = (tt < 16) ? g_w2 : g_w3;
    short* Wt = (tt < 16) ? W2t : W3t;
    tt &= 15;
    int k0 = (tt >> 2) * 64, n0 = (tt & 3) * 64;
    for (int p = 0; p < 16; p++) {
      int kl = p * 4 + r4;
      tile[kl * 66 + nc] = f2bf(W[(size_t)(k0 + kl) * 256 + n0 + nc]);
    }
    __syncthreads();
    for (int p = 0; p < 16; p++) {
      int nl = p * 4 + r4;
      Wt[(size_t)(n0 + nl) * 256 + k0 + nc] = tile[nc * 66 + nl];
    }
    return;
  }
  // zero rel: 8 blocks x 256 threads x 1 float4
  {
    int bb = blk - 380;
    ((f32x4*)rel)[bb * 256 + t] = (f32x4){0.f, 0.f, 0.f, 0.f};
  }
}

// ---------------- u/v GEMM: uv[m][0:256]=x@W_a, uv[m][256:512]=x@W_b + b1 ----------------
// one wave per block, 256 blocks (32 m-tiles x 8 n-tiles)

__global__ __launch_bounds__(64)
void uv_gemm(const short* __restrict__ xb, const short* __restrict__ Wab,
             const float* __restrict__ g_b1, float* __restrict__ uv) {
  const int m0 = blockIdx.x * 64;
  const int n0 = blockIdx.y * 64;
  const int lane = threadIdx.x;
  const int q = lane >> 4, l16 = lane & 15;

  f32x4 acc[4][4];
#pragma unroll
  for (int mt = 0; mt < 4; mt++)
#pragma unroll
    for (int nt = 0; nt < 4; nt++) acc[mt][nt] = (f32x4){0.f, 0.f, 0.f, 0.f};

  for (int k0 = 0; k0 < KX; k0 += 32) {
    frag8 a[4], bb[4];
#pragma unroll
    for (int mt = 0; mt < 4; mt++)
      a[mt] = *(const frag8*)(xb + (size_t)(m0 + mt * 16 + l16) * KX + k0 + q * 8);
#pragma unroll
    for (int nt = 0; nt < 4; nt++)
      bb[nt] = *(const frag8*)(Wab + (size_t)(n0 + nt * 16 + l16) * KX + k0 + q * 8);
#pragma unroll
    for (int mt = 0; mt < 4; mt++)
#pragma unroll
      for (int nt = 0; nt < 4; nt++)
        acc[mt][nt] = __builtin_amdgcn_mfma_f32_16x16x32_bf16(a[mt], bb[nt], acc[mt][nt], 0, 0, 0);
  }
#pragma unroll
  for (int nt = 0; nt < 4; nt++) {
    int col = n0 + nt * 16 + l16;
    float bias = (col >= 256) ? g_b1[col - 256] : 0.f;
#pragma unroll
    for (int mt = 0; mt < 4; mt++) {
      int m = m0 + mt * 16 + q * 4;
#pragma unroll
      for (int r = 0; r < 4; r++)
        uv[(size_t)(m + r) * 512 + col] = acc[mt][nt][r] + bias;
    }
  }
}

// ---------------- main fused relation kernel ----------------
// block = (b, i). One LDS union buffer:
//   A view: chunk1 row j at lds[j*AS1] (192 elems), chunk2 at lds[A2OFF + j*AS2] (96)
//   H view: row r at lds[r*HS] (256 elems) -- written only after all A reads done.

#define AS1 200   // 400B row = 25*16
#define AS2 104   // 208B row = 13*16
#define A2OFF (64 * AS1)
#define HS 264    // 528B row = 33*16
#define LDS_SHORTS (64 * AS1 + 64 * AS2)  // 19456 shorts = 38912 B -> 4 blocks/CU

__global__ __launch_bounds__(256, 4)
void relnet_main(const short* __restrict__ xb, const short* __restrict__ Wc,
                 const short* __restrict__ W2t, const short* __restrict__ W3t,
                 const float* __restrict__ uv, const float* __restrict__ g_b2,
                 const float* __restrict__ g_b3, float* __restrict__ rel) {
  __shared__ short lds[LDS_SHORTS];

  const int tid = threadIdx.x;
  const int bi = blockIdx.x;
  const int b = bi >> 6, i = bi & 63;
  const int lane = tid & 63, wave = tid >> 6;
  const int q = lane >> 4, l16 = lane & 15;
  const int n0 = wave * 64;
  const int rowbase = b * 64;
  const short* xi = xb + (size_t)(rowbase + i) * KX;

  f32x4 acc[4][4];
#pragma unroll
  for (int mt = 0; mt < 4; mt++)
#pragma unroll
    for (int nt = 0; nt < 4; nt++) acc[mt][nt] = (f32x4){0.f, 0.f, 0.f, 0.f};

  // ---- stage ALL pair products (both chunks) ----
  for (int idx = tid; idx < 64 * 48; idx += 256) {
    int j = idx / 48, k4 = (idx - j * 48) * 4;
    s4 aj = *(const s4*)(xb + (size_t)(rowbase + j) * KX + k4);
    s4 ai = *(const s4*)(xi + k4);
    s4 r;
#pragma unroll
    for (int t = 0; t < 4; t++) r[t] = f2bf(bf2f(aj[t]) * bf2f(ai[t]));
    *(s4*)(&lds[j * AS1 + k4]) = r;
  }
  for (int idx = tid; idx < 64 * 24; idx += 256) {
    int j = idx / 24, k4 = (idx - j * 24) * 4;
    s4 aj = *(const s4*)(xb + (size_t)(rowbase + j) * KX + 192 + k4);
    s4 ai = *(const s4*)(xi + 192 + k4);
    s4 r;
#pragma unroll
    for (int t = 0; t < 4; t++) r[t] = f2bf(bf2f(aj[t]) * bf2f(ai[t]));
    *(s4*)(&lds[A2OFF + j * AS2 + k4]) = r;
  }
  __syncthreads();

  // ---- layer 1 MFMA: 6 k-steps chunk1 + 3 k-steps chunk2 ----
  for (int k0 = 0; k0 < 192; k0 += 32) {
    frag8 a[4], bb[4];
#pragma unroll
    for (int mt = 0; mt < 4; mt++)
      a[mt] = *(const frag8*)(&lds[(mt * 16 + l16) * AS1 + k0 + q * 8]);
#pragma unroll
    for (int nt = 0; nt < 4; nt++)
      bb[nt] = *(const frag8*)(Wc + (size_t)(n0 + nt * 16 + l16) * KX + k0 + q * 8);
#pragma unroll
    for (int mt = 0; mt < 4; mt++)
#pragma unroll
      for (int nt = 0; nt < 4; nt++)
        acc[mt][nt] = __builtin_amdgcn_mfma_f32_16x16x32_bf16(a[mt], bb[nt], acc[mt][nt], 0, 0, 0);
  }
  for (int k0 = 0; k0 < 96; k0 += 32) {
    frag8 a[4], bb[4];
#pragma unroll
    for (int mt = 0; mt < 4; mt++)
      a[mt] = *(const frag8*)(&lds[A2OFF + (mt * 16 + l16) * AS2 + k0 + q * 8]);
#pragma unroll
    for (int nt = 0; nt < 4; nt++)
      bb[nt] = *(const frag8*)(Wc + (size_t)(n0 + nt * 16 + l16) * KX + 192 + k0 + q * 8);
#pragma unroll
    for (int mt = 0; mt < 4; mt++)
#pragma unroll
      for (int nt = 0; nt < 4; nt++)
        acc[mt][nt] = __builtin_amdgcn_mfma_f32_16x16x32_bf16(a[mt], bb[nt], acc[mt][nt], 0, 0, 0);
  }
  __syncthreads();  // all waves done reading A before H overwrites the union

  // ---- layer 1 epilogue: h1 = relu(acc + u[j] + v[i] + b1) -> H (bf16) ----
  {
    const float* ub = uv + (size_t)rowbase * 512;
    const float* vp = uv + (size_t)(rowbase + i) * 512 + 256;  // v + b1 already
#pragma unroll
    for (int nt = 0; nt < 4; nt++) {
      int col = n0 + nt * 16 + l16;
      float vv = vp[col];
#pragma unroll
      for (int mt = 0; mt < 4; mt++) {
        int jb = mt * 16 + q * 4;
#pragma unroll
        for (int r = 0; r < 4; r++) {
          float val = acc[mt][nt][r] + ub[(size_t)(jb + r) * 512 + col] + vv;
          lds[(jb + r) * HS + col] = f2bf(fmaxf(val, 0.f));
        }
        acc[mt][nt] = (f32x4){0.f, 0.f, 0.f, 0.f};
      }
    }
  }
  __syncthreads();

  // ---- layer 2: h2 = relu(h1 @ W2 + b2) ----
  for (int k0 = 0; k0 < 256; k0 += 32) {
    frag8 a[4], bb[4];
#pragma unroll
    for (int mt = 0; mt < 4; mt++)
      a[mt] = *(const frag8*)(&lds[(mt * 16 + l16) * HS + k0 + q * 8]);
#pragma unroll
    for (int nt = 0; nt < 4; nt++)
      bb[nt] = *(const frag8*)(W2t + (size_t)(n0 + nt * 16 + l16) * 256 + k0 + q * 8);
#pragma unroll
    for (int mt = 0; mt < 4; mt++)
#pragma unroll
      for (int nt = 0; nt < 4; nt++)
        acc[mt][nt] = __builtin_amdgcn_mfma_f32_16x16x32_bf16(a[mt], bb[nt], acc[mt][nt], 0, 0, 0);
  }
  __syncthreads();  // all waves done READING h1 before overwriting with h2
#pragma unroll
  for (int nt = 0; nt < 4; nt++) {
    int col = n0 + nt * 16 + l16;
    float b2 = g_b2[col];
#pragma unroll
    for (int mt = 0; mt < 4; mt++) {
      int jb = mt * 16 + q * 4;
#pragma unroll
      for (int r = 0; r < 4; r++)
        lds[(jb + r) * HS + col] = f2bf(fmaxf(acc[mt][nt][r] + b2, 0.f));
      acc[mt][nt] = (f32x4){0.f, 0.f, 0.f, 0.f};
    }
  }
  __syncthreads();

  // ---- layer 3: h3 = relu(h2 @ W3 + b3), reduce over j, atomic into rel ----
  for (int k0 = 0; k0 < 256; k0 += 32) {
    frag8 a[4], bb[4];
#pragma unroll
    for (int mt = 0; mt < 4; mt++)
      a[mt] = *(const frag8*)(&lds[(mt * 16 + l16) * HS + k0 + q * 8]);
#pragma unroll
    for (int nt = 0; nt < 4; nt++)
      bb[nt] = *(const frag8*)(W3t + (size_t)(n0 + nt * 16 + l16) * 256 + k0 + q * 8);
#pragma unroll
    for (int mt = 0; mt < 4; mt++)
#pragma unroll
      for (int nt = 0; nt < 4; nt++)
        acc[mt][nt] = __builtin_amdgcn_mfma_f32_16x16x32_bf16(a[mt], bb[nt], acc[mt][nt], 0, 0, 0);
  }
#pragma unroll
  for (int nt = 0; nt < 4; nt++) {
    int col = n0 + nt * 16 + l16;
    float b3 = g_b3[col];
    float s = 0.f;
#pragma unroll
    for (int mt = 0; mt < 4; mt++)
#pragma unroll
      for (int r = 0; r < 4; r++)
        s += fmaxf(acc[mt][nt][r] + b3, 0.f);
    s += __shfl_xor(s, 16, 64);
    s += __shfl_xor(s, 32, 64);
    if (q == 0) atomicAdd(&rel[b * 256 + col], s);
  }
}

// ---------------- f-network (fp32, exact) ----------------
__global__ __launch_bounds__(256)
void fnet(const float* __restrict__ rel, const float* __restrict__ f_w1,
          const float* __restrict__ f_b1, const float* __restrict__ f_w2,
          const float* __restrict__ f_b2, const float* __restrict__ f_w3,
          const float* __restrict__ f_b3, float* __restrict__ out) {
  int b = blockIdx.x, t = threadIdx.x;
  __shared__ float y0[256], y1[256], y2[256];
  y0[t] = rel[b * 256 + t];
  __syncthreads();
  float s = f_b1[t];
#pragma unroll 8
  for (int k = 0; k < 256; k++) s += y0[k] * f_w1[k * 256 + t];
  y1[t] = fmaxf(s, 0.f);
  __syncthreads();
  s = f_b2[t];
#pragma unroll 8
  for (int k = 0; k < 256; k++) s += y1[k] * f_w2[k * 256 + t];
  y2[t] = fmaxf(s, 0.f);
  __syncthreads();
  if (t < 10) {
    float s2 = f_b3[t];
#pragma unroll 8
    for (int k = 0; k < 256; k++) s2 += y2[k] * f_w3[k * 10 + t];
    out[b * 10 + t] = s2;
  }
}

// ---------------- launch ----------------
extern "C" void kernel_launch(void* const* d_in, const int* in_sizes, int n_in,
                              void* d_out, int out_size, void* d_ws, size_t ws_size,
                              hipStream_t stream) {
  const float* sent  = (const float*)d_in[0];
  const float* coord = (const float*)d_in[1];
  const float* g_w1  = (const float*)d_in[2];
  const float* g_b1  = (const float*)d_in[3];
  const float* g_w2  = (const float*)d_in[4];
  const float* g_b2  = (const float*)d_in[5];
  const float* g_w3  = (const float*)d_in[6];
  const float* g_b3  = (const float*)d_in[7];
  const float* f_w1  = (const float*)d_in[8];
  const float* f_b1  = (const float*)d_in[9];
  const float* f_w2  = (const float*)d_in[10];
  const float* f_b2  = (const float*)d_in[11];
  const float* f_w3  = (const float*)d_in[12];
  const float* f_b3  = (const float*)d_in[13];
  float* out = (float*)d_out;

  char* ws = (char*)d_ws;
  size_t off = 0;
  auto alloc = [&](size_t bytes) {
    char* p = ws + off;
    off += (bytes + 255) & ~(size_t)255;
    return p;
  };
  short* xb  = (short*)alloc((size_t)2048 * KX * 2);
  short* Wab = (short*)alloc((size_t)512 * KX * 2);
  short* Wc  = (short*)alloc((size_t)256 * KX * 2);
  short* W2t = (short*)alloc((size_t)256 * 256 * 2);
  short* W3t = (short*)alloc((size_t)256 * 256 * 2);
  float* uv  = (float*)alloc((size_t)2048 * 512 * 4);
  float* rel = (float*)alloc((size_t)32 * 256 * 4);

  prep<<<388, 256, 0, stream>>>(sent, coord, g_w1, g_w2, g_w3, xb, Wab, Wc, W2t, W3t, rel);
  uv_gemm<<<dim3(32, 8), 64, 0, stream>>>(xb, Wab, g_b1, uv);
  relnet_main<<<2048, 256, 0, stream>>>(xb, Wc, W2t, W3t, uv, g_b2, g_b3, rel);
  fnet<<<32, 256, 0, stream>>>(rel, f_w1, f_b1, f_w2, f_b2, f_w3, f_b3, out);
}

// Round 3
// 228.718 us; speedup vs baseline: 1.0774x; 1.0119x over previous
//
#include <hip/hip_runtime.h>
#include <hip/hip_bf16.h>

// RelationsNetwork on MI355X.
// Decomposition: h1 = relu(u[j] + v[i] + (x_i*x_j)@W_c + b1), u=x@W_a, v=x@W_b
// where g_w1 = [W_a; W_b; W_c] (rows 0:258, 258:516, 516:774).
// Main kernel: one block per (b,i); fused 3-layer MFMA GEMM chain in LDS;
// A-products and H buffers ALIASED in one LDS union (38912 B).
// Occupancy history: (256,2)=2 blk/CU no-spill 136us; (256,4)=4 blk/CU but
// 128-reg cap forced ~85MB scratch spill (WRITE_SIZE 2->59MB), 122us.
// This round: (256,3) -> cap ~170 regs, fits 64 AGPR + ~92 VGPR, no spill,
// 3 blk/CU. j-reduction in-register; atomicAdd into rel[b,h]. K padded 258->288.

typedef __attribute__((ext_vector_type(4))) float f32x4;
typedef __attribute__((ext_vector_type(8))) short frag8;  // 8 bf16 = 4 VGPR
typedef __attribute__((ext_vector_type(4))) short s4;     // 8 bytes

__device__ __forceinline__ float bf2f(short s) {
  return __uint_as_float(((unsigned)(unsigned short)s) << 16);
}
__device__ __forceinline__ short f2bf(float f) {
  unsigned u = __float_as_uint(f);
  return (short)((u + 0x7fffu + ((u >> 16) & 1u)) >> 16);
}

#define KX 288   // padded 258 -> 288 (mult of 32)

// ---------------- merged prep kernel ----------------
// regions by blockIdx.x:
//   [0,288)    build_x:  xb[(b*64+s)*288+k] = bf16(x[b,s,k])
//   [288,328)  Wab:  [n][k] n<256 -> W_a col n ; n>=256 -> W_b col n-256
//   [328,348)  Wc:   [n][k] = g_w1[516+k][n]
//   [348,364)  W2t:  [n][k] = g_w2[k][n]
//   [364,380)  W3t:  [n][k] = g_w3[k][n]
//   [380,388)  zero rel
__global__ __launch_bounds__(256)
void prep(const float* __restrict__ sent, const float* __restrict__ coord,
          const float* __restrict__ g_w1, const float* __restrict__ g_w2,
          const float* __restrict__ g_w3,
          short* __restrict__ xb, short* __restrict__ Wab, short* __restrict__ Wc,
          short* __restrict__ W2t, short* __restrict__ W3t, float* __restrict__ rel) {
  __shared__ short tile[64 * 66];  // odd-dword stride: conflict-free transpose
  const int blk = blockIdx.x, t = threadIdx.x;

  if (blk < 288) {
    long idx0 = ((long)blk * 256 + t) * 8;
#pragma unroll
    for (int e = 0; e < 8; e++) {
      long idx = idx0 + e;
      int row = (int)(idx / KX), k = (int)(idx - (long)row * KX);
      float v = 0.f;
      if (k < 256)      v = sent[(size_t)row * 256 + k];
      else if (k < 258) v = coord[row * 2 + (k - 256)];
      xb[idx] = f2bf(v);
    }
    return;
  }

  const int nc = t & 63, r4 = t >> 6;  // read: 4 rows x 64 cols per pass
  if (blk < 328) {  // Wab
    int tt = blk - 288, kt = tt >> 3, nt = tt & 7;
    int k0 = kt * 64, n0 = nt * 64;
    for (int p = 0; p < 16; p++) {
      int kl = p * 4 + r4, k = k0 + kl, n = n0 + nc;
      float v = 0.f;
      if (k < 258) {
        int row = (n < 256) ? k : 258 + k;
        int col = (n < 256) ? n : n - 256;
        v = g_w1[(size_t)row * 256 + col];
      }
      tile[kl * 66 + nc] = f2bf(v);
    }
    __syncthreads();
    for (int p = 0; p < 16; p++) {
      int nl = p * 4 + r4;
      if (k0 + nc < KX) Wab[(size_t)(n0 + nl) * KX + k0 + nc] = tile[nc * 66 + nl];
    }
    return;
  }
  if (blk < 348) {  // Wc
    int tt = blk - 328, kt = tt >> 2, nt = tt & 3;
    int k0 = kt * 64, n0 = nt * 64;
    for (int p = 0; p < 16; p++) {
      int kl = p * 4 + r4, k = k0 + kl;
      float v = (k < 258) ? g_w1[(size_t)(516 + k) * 256 + n0 + nc] : 0.f;
      tile[kl * 66 + nc] = f2bf(v);
    }
    __syncthreads();
    for (int p = 0; p < 16; p++) {
      int nl = p * 4 + r4;
      if (k0 + nc < KX) Wc[(size_t)(n0 + nl) * KX + k0 + nc] = tile[nc * 66 + nl];
    }
    return;
  }
  if (blk < 380) {  // W2t / W3t
    int tt = blk - 348;
    const float* W = (tt < 16) ? g_w2 : g_w3;
    short* Wt = (tt < 16) ? W2t : W3t;
    tt &= 15;
    int k0 = (tt >> 2) * 64, n0 = (tt & 3) * 64;
    for (int p = 0; p < 16; p++) {
      int kl = p * 4 + r4;
      tile[kl * 66 + nc] = f2bf(W[(size_t)(k0 + kl) * 256 + n0 + nc]);
    }
    __syncthreads();
    for (int p = 0; p < 16; p++) {
      int nl = p * 4 + r4;
      Wt[(size_t)(n0 + nl) * 256 + k0 + nc] = tile[nc * 66 + nl];
    }
    return;
  }
  // zero rel: 8 blocks x 256 threads x 1 float4
  {
    int bb = blk - 380;
    ((f32x4*)rel)[bb * 256 + t] = (f32x4){0.f, 0.f, 0.f, 0.f};
  }
}

// ---------------- u/v GEMM: uv[m][0:256]=x@W_a, uv[m][256:512]=x@W_b + b1 ----------------
// one wave per block, 256 blocks (32 m-tiles x 8 n-tiles)

__global__ __launch_bounds__(64)
void uv_gemm(const short* __restrict__ xb, const short* __restrict__ Wab,
             const float* __restrict__ g_b1, float* __restrict__ uv) {
  const int m0 = blockIdx.x * 64;
  const int n0 = blockIdx.y * 64;
  const int lane = threadIdx.x;
  const int q = lane >> 4, l16 = lane & 15;

  f32x4 acc[4][4];
#pragma unroll
  for (int mt = 0; mt < 4; mt++)
#pragma unroll
    for (int nt = 0; nt < 4; nt++) acc[mt][nt] = (f32x4){0.f, 0.f, 0.f, 0.f};

  for (int k0 = 0; k0 < KX; k0 += 32) {
    frag8 a[4], bb[4];
#pragma unroll
    for (int mt = 0; mt < 4; mt++)
      a[mt] = *(const frag8*)(xb + (size_t)(m0 + mt * 16 + l16) * KX + k0 + q * 8);
#pragma unroll
    for (int nt = 0; nt < 4; nt++)
      bb[nt] = *(const frag8*)(Wab + (size_t)(n0 + nt * 16 + l16) * KX + k0 + q * 8);
#pragma unroll
    for (int mt = 0; mt < 4; mt++)
#pragma unroll
      for (int nt = 0; nt < 4; nt++)
        acc[mt][nt] = __builtin_amdgcn_mfma_f32_16x16x32_bf16(a[mt], bb[nt], acc[mt][nt], 0, 0, 0);
  }
#pragma unroll
  for (int nt = 0; nt < 4; nt++) {
    int col = n0 + nt * 16 + l16;
    float bias = (col >= 256) ? g_b1[col - 256] : 0.f;
#pragma unroll
    for (int mt = 0; mt < 4; mt++) {
      int m = m0 + mt * 16 + q * 4;
#pragma unroll
      for (int r = 0; r < 4; r++)
        uv[(size_t)(m + r) * 512 + col] = acc[mt][nt][r] + bias;
    }
  }
}

// ---------------- main fused relation kernel ----------------
// block = (b, i). One LDS union buffer:
//   A view: chunk1 row j at lds[j*AS1] (192 elems), chunk2 at lds[A2OFF + j*AS2] (96)
//   H view: row r at lds[r*HS] (256 elems) -- written only after all A reads done.

#define AS1 200   // 400B row = 25*16
#define AS2 104   // 208B row = 13*16
#define A2OFF (64 * AS1)
#define HS 264    // 528B row = 33*16
#define LDS_SHORTS (64 * AS1 + 64 * AS2)  // 19456 shorts = 38912 B

__global__ __launch_bounds__(256, 3)
void relnet_main(const short* __restrict__ xb, const short* __restrict__ Wc,
                 const short* __restrict__ W2t, const short* __restrict__ W3t,
                 const float* __restrict__ uv, const float* __restrict__ g_b2,
                 const float* __restrict__ g_b3, float* __restrict__ rel) {
  __shared__ short lds[LDS_SHORTS];

  const int tid = threadIdx.x;
  const int bi = blockIdx.x;
  const int b = bi >> 6, i = bi & 63;
  const int lane = tid & 63, wave = tid >> 6;
  const int q = lane >> 4, l16 = lane & 15;
  const int n0 = wave * 64;
  const int rowbase = b * 64;
  const short* xi = xb + (size_t)(rowbase + i) * KX;

  f32x4 acc[4][4];
#pragma unroll
  for (int mt = 0; mt < 4; mt++)
#pragma unroll
    for (int nt = 0; nt < 4; nt++) acc[mt][nt] = (f32x4){0.f, 0.f, 0.f, 0.f};

  // ---- stage ALL pair products (both chunks) ----
  for (int idx = tid; idx < 64 * 48; idx += 256) {
    int j = idx / 48, k4 = (idx - j * 48) * 4;
    s4 aj = *(const s4*)(xb + (size_t)(rowbase + j) * KX + k4);
    s4 ai = *(const s4*)(xi + k4);
    s4 r;
#pragma unroll
    for (int t = 0; t < 4; t++) r[t] = f2bf(bf2f(aj[t]) * bf2f(ai[t]));
    *(s4*)(&lds[j * AS1 + k4]) = r;
  }
  for (int idx = tid; idx < 64 * 24; idx += 256) {
    int j = idx / 24, k4 = (idx - j * 24) * 4;
    s4 aj = *(const s4*)(xb + (size_t)(rowbase + j) * KX + 192 + k4);
    s4 ai = *(const s4*)(xi + 192 + k4);
    s4 r;
#pragma unroll
    for (int t = 0; t < 4; t++) r[t] = f2bf(bf2f(aj[t]) * bf2f(ai[t]));
    *(s4*)(&lds[A2OFF + j * AS2 + k4]) = r;
  }
  __syncthreads();

  // ---- layer 1 MFMA: 6 k-steps chunk1 + 3 k-steps chunk2 ----
  for (int k0 = 0; k0 < 192; k0 += 32) {
    frag8 a[4], bb[4];
#pragma unroll
    for (int mt = 0; mt < 4; mt++)
      a[mt] = *(const frag8*)(&lds[(mt * 16 + l16) * AS1 + k0 + q * 8]);
#pragma unroll
    for (int nt = 0; nt < 4; nt++)
      bb[nt] = *(const frag8*)(Wc + (size_t)(n0 + nt * 16 + l16) * KX + k0 + q * 8);
#pragma unroll
    for (int mt = 0; mt < 4; mt++)
#pragma unroll
      for (int nt = 0; nt < 4; nt++)
        acc[mt][nt] = __builtin_amdgcn_mfma_f32_16x16x32_bf16(a[mt], bb[nt], acc[mt][nt], 0, 0, 0);
  }
  for (int k0 = 0; k0 < 96; k0 += 32) {
    frag8 a[4], bb[4];
#pragma unroll
    for (int mt = 0; mt < 4; mt++)
      a[mt] = *(const frag8*)(&lds[A2OFF + (mt * 16 + l16) * AS2 + k0 + q * 8]);
#pragma unroll
    for (int nt = 0; nt < 4; nt++)
      bb[nt] = *(const frag8*)(Wc + (size_t)(n0 + nt * 16 + l16) * KX + 192 + k0 + q * 8);
#pragma unroll
    for (int mt = 0; mt < 4; mt++)
#pragma unroll
      for (int nt = 0; nt < 4; nt++)
        acc[mt][nt] = __builtin_amdgcn_mfma_f32_16x16x32_bf16(a[mt], bb[nt], acc[mt][nt], 0, 0, 0);
  }
  __syncthreads();  // all waves done reading A before H overwrites the union

  // ---- layer 1 epilogue: h1 = relu(acc + u[j] + v[i] + b1) -> H (bf16) ----
  {
    const float* ub = uv + (size_t)rowbase * 512;
    const float* vp = uv + (size_t)(rowbase + i) * 512 + 256;  // v + b1 already
#pragma unroll
    for (int nt = 0; nt < 4; nt++) {
      int col = n0 + nt * 16 + l16;
      float vv = vp[col];
#pragma unroll
      for (int mt = 0; mt < 4; mt++) {
        int jb = mt * 16 + q * 4;
#pragma unroll
        for (int r = 0; r < 4; r++) {
          float val = acc[mt][nt][r] + ub[(size_t)(jb + r) * 512 + col] + vv;
          lds[(jb + r) * HS + col] = f2bf(fmaxf(val, 0.f));
        }
        acc[mt][nt] = (f32x4){0.f, 0.f, 0.f, 0.f};
      }
    }
  }
  __syncthreads();

  // ---- layer 2: h2 = relu(h1 @ W2 + b2) ----
  for (int k0 = 0; k0 < 256; k0 += 32) {
    frag8 a[4], bb[4];
#pragma unroll
    for (int mt = 0; mt < 4; mt++)
      a[mt] = *(const frag8*)(&lds[(mt * 16 + l16) * HS + k0 + q * 8]);
#pragma unroll
    for (int nt = 0; nt < 4; nt++)
      bb[nt] = *(const frag8*)(W2t + (size_t)(n0 + nt * 16 + l16) * 256 + k0 + q * 8);
#pragma unroll
    for (int mt = 0; mt < 4; mt++)
#pragma unroll
      for (int nt = 0; nt < 4; nt++)
        acc[mt][nt] = __builtin_amdgcn_mfma_f32_16x16x32_bf16(a[mt], bb[nt], acc[mt][nt], 0, 0, 0);
  }
  __syncthreads();  // all waves done READING h1 before overwriting with h2
#pragma unroll
  for (int nt = 0; nt < 4; nt++) {
    int col = n0 + nt * 16 + l16;
    float b2 = g_b2[col];
#pragma unroll
    for (int mt = 0; mt < 4; mt++) {
      int jb = mt * 16 + q * 4;
#pragma unroll
      for (int r = 0; r < 4; r++)
        lds[(jb + r) * HS + col] = f2bf(fmaxf(acc[mt][nt][r] + b2, 0.f));
      acc[mt][nt] = (f32x4){0.f, 0.f, 0.f, 0.f};
    }
  }
  __syncthreads();

  // ---- layer 3: h3 = relu(h2 @ W3 + b3), reduce over j, atomic into rel ----
  for (int k0 = 0; k0 < 256; k0 += 32) {
    frag8 a[4], bb[4];
#pragma unroll
    for (int mt = 0; mt < 4; mt++)
      a[mt] = *(const frag8*)(&lds[(mt * 16 + l16) * HS + k0 + q * 8]);
#pragma unroll
    for (int nt = 0; nt < 4; nt++)
      bb[nt] = *(const frag8*)(W3t + (size_t)(n0 + nt * 16 + l16) * 256 + k0 + q * 8);
#pragma unroll
    for (int mt = 0; mt < 4; mt++)
#pragma unroll
      for (int nt = 0; nt < 4; nt++)
        acc[mt][nt] = __builtin_amdgcn_mfma_f32_16x16x32_bf16(a[mt], bb[nt], acc[mt][nt], 0, 0, 0);
  }
#pragma unroll
  for (int nt = 0; nt < 4; nt++) {
    int col = n0 + nt * 16 + l16;
    float b3 = g_b3[col];
    float s = 0.f;
#pragma unroll
    for (int mt = 0; mt < 4; mt++)
#pragma unroll
      for (int r = 0; r < 4; r++)
        s += fmaxf(acc[mt][nt][r] + b3, 0.f);
    s += __shfl_xor(s, 16, 64);
    s += __shfl_xor(s, 32, 64);
    if (q == 0) atomicAdd(&rel[b * 256 + col], s);
  }
}

// ---------------- f-network (fp32, exact) ----------------
__global__ __launch_bounds__(256)
void fnet(const float* __restrict__ rel, const float* __restrict__ f_w1,
          const float* __restrict__ f_b1, const float* __restrict__ f_w2,
          const float* __restrict__ f_b2, const float* __restrict__ f_w3,
          const float* __restrict__ f_b3, float* __restrict__ out) {
  int b = blockIdx.x, t = threadIdx.x;
  __shared__ float y0[256], y1[256], y2[256];
  y0[t] = rel[b * 256 + t];
  __syncthreads();
  float s = f_b1[t];
#pragma unroll 8
  for (int k = 0; k < 256; k++) s += y0[k] * f_w1[k * 256 + t];
  y1[t] = fmaxf(s, 0.f);
  __syncthreads();
  s = f_b2[t];
#pragma unroll 8
  for (int k = 0; k < 256; k++) s += y1[k] * f_w2[k * 256 + t];
  y2[t] = fmaxf(s, 0.f);
  __syncthreads();
  if (t < 10) {
    float s2 = f_b3[t];
#pragma unroll 8
    for (int k = 0; k < 256; k++) s2 += y2[k] * f_w3[k * 10 + t];
    out[b * 10 + t] = s2;
  }
}

// ---------------- launch ----------------
extern "C" void kernel_launch(void* const* d_in, const int* in_sizes, int n_in,
                              void* d_out, int out_size, void* d_ws, size_t ws_size,
                              hipStream_t stream) {
  const float* sent  = (const float*)d_in[0];
  const float* coord = (const float*)d_in[1];
  const float* g_w1  = (const float*)d_in[2];
  const float* g_b1  = (const float*)d_in[3];
  const float* g_w2  = (const float*)d_in[4];
  const float* g_b2  = (const float*)d_in[5];
  const float* g_w3  = (const float*)d_in[6];
  const float* g_b3  = (const float*)d_in[7];
  const float* f_w1  = (const float*)d_in[8];
  const float* f_b1  = (const float*)d_in[9];
  const float* f_w2  = (const float*)d_in[10];
  const float* f_b2  = (const float*)d_in[11];
  const float* f_w3  = (const float*)d_in[12];
  const float* f_b3  = (const float*)d_in[13];
  float* out = (float*)d_out;

  char* ws = (char*)d_ws;
  size_t off = 0;
  auto alloc = [&](size_t bytes) {
    char* p = ws + off;
    off += (bytes + 255) & ~(size_t)255;
    return p;
  };
  short* xb  = (short*)alloc((size_t)2048 * KX * 2);
  short* Wab = (short*)alloc((size_t)512 * KX * 2);
  short* Wc  = (short*)alloc((size_t)256 * KX * 2);
  short* W2t = (short*)alloc((size_t)256 * 256 * 2);
  short* W3t = (short*)alloc((size_t)256 * 256 * 2);
  float* uv  = (float*)alloc((size_t)2048 * 512 * 4);
  float* rel = (float*)alloc((size_t)32 * 256 * 4);

  prep<<<388, 256, 0, stream>>>(sent, coord, g_w1, g_w2, g_w3, xb, Wab, Wc, W2t, W3t, rel);
  uv_gemm<<<dim3(32, 8), 64, 0, stream>>>(xb, Wab, g_b1, uv);
  relnet_main<<<2048, 256, 0, stream>>>(xb, Wc, W2t, W3t, uv, g_b2, g_b3, rel);
  fnet<<<32, 256, 0, stream>>>(rel, f_w1, f_b1, f_w2, f_b2, f_w3, f_b3, out);
}

// Round 4
// 214.302 us; speedup vs baseline: 1.1498x; 1.0673x over previous
//
#include <hip/hip_runtime.h>
#include <hip/hip_bf16.h>

// RelationsNetwork on MI355X.
// Decomposition: h1 = relu(u[j] + v[i] + (x_i*x_j)@W_c + b1), u=x@W_a, v=x@W_b
// where g_w1 = [W_a; W_b; W_c] (rows 0:258, 258:516, 516:774).
// Main kernel: one block per (b,i); fused 3-layer MFMA GEMM chain.
// Round-4: explicit 2-deep software pipeline in every k-loop (prefetch next
// A-frags from LDS + B-frags from L2 before current MFMAs) — round-3 counters
// showed ~4k cyc/k-step vs ~78 cyc MFMA: serialized load->MFMA chains.
// Unified LDS union: A rows (288) and H rows (256) share stride-296 buffer,
// 37888 B. (256,3): 64 AGPR + ~86 VGPR fits 170-reg cap, no spill
// (round-2 (256,4) spilled 85MB; round-3 (256,3) clean).

typedef __attribute__((ext_vector_type(4))) float f32x4;
typedef __attribute__((ext_vector_type(8))) short frag8;  // 8 bf16 = 4 VGPR

__device__ __forceinline__ float bf2f(short s) {
  return __uint_as_float(((unsigned)(unsigned short)s) << 16);
}
__device__ __forceinline__ short f2bf(float f) {
  unsigned u = __float_as_uint(f);
  return (short)((u + 0x7fffu + ((u >> 16) & 1u)) >> 16);
}

#define KX 288   // padded 258 -> 288 (mult of 32)

// ---------------- merged prep kernel ----------------
// regions by blockIdx.x:
//   [0,288)    build_x:  xb[(b*64+s)*288+k] = bf16(x[b,s,k])
//   [288,328)  Wab:  [n][k] n<256 -> W_a col n ; n>=256 -> W_b col n-256
//   [328,348)  Wc:   [n][k] = g_w1[516+k][n]
//   [348,364)  W2t:  [n][k] = g_w2[k][n]
//   [364,380)  W3t:  [n][k] = g_w3[k][n]
//   [380,388)  zero rel
__global__ __launch_bounds__(256)
void prep(const float* __restrict__ sent, const float* __restrict__ coord,
          const float* __restrict__ g_w1, const float* __restrict__ g_w2,
          const float* __restrict__ g_w3,
          short* __restrict__ xb, short* __restrict__ Wab, short* __restrict__ Wc,
          short* __restrict__ W2t, short* __restrict__ W3t, float* __restrict__ rel) {
  __shared__ short tile[64 * 66];  // odd-dword stride: conflict-free transpose
  const int blk = blockIdx.x, t = threadIdx.x;

  if (blk < 288) {
    long idx0 = ((long)blk * 256 + t) * 8;
#pragma unroll
    for (int e = 0; e < 8; e++) {
      long idx = idx0 + e;
      int row = (int)(idx / KX), k = (int)(idx - (long)row * KX);
      float v = 0.f;
      if (k < 256)      v = sent[(size_t)row * 256 + k];
      else if (k < 258) v = coord[row * 2 + (k - 256)];
      xb[idx] = f2bf(v);
    }
    return;
  }

  const int nc = t & 63, r4 = t >> 6;  // read: 4 rows x 64 cols per pass
  if (blk < 328) {  // Wab
    int tt = blk - 288, kt = tt >> 3, nt = tt & 7;
    int k0 = kt * 64, n0 = nt * 64;
    for (int p = 0; p < 16; p++) {
      int kl = p * 4 + r4, k = k0 + kl, n = n0 + nc;
      float v = 0.f;
      if (k < 258) {
        int row = (n < 256) ? k : 258 + k;
        int col = (n < 256) ? n : n - 256;
        v = g_w1[(size_t)row * 256 + col];
      }
      tile[kl * 66 + nc] = f2bf(v);
    }
    __syncthreads();
    for (int p = 0; p < 16; p++) {
      int nl = p * 4 + r4;
      if (k0 + nc < KX) Wab[(size_t)(n0 + nl) * KX + k0 + nc] = tile[nc * 66 + nl];
    }
    return;
  }
  if (blk < 348) {  // Wc
    int tt = blk - 328, kt = tt >> 2, nt = tt & 3;
    int k0 = kt * 64, n0 = nt * 64;
    for (int p = 0; p < 16; p++) {
      int kl = p * 4 + r4, k = k0 + kl;
      float v = (k < 258) ? g_w1[(size_t)(516 + k) * 256 + n0 + nc] : 0.f;
      tile[kl * 66 + nc] = f2bf(v);
    }
    __syncthreads();
    for (int p = 0; p < 16; p++) {
      int nl = p * 4 + r4;
      if (k0 + nc < KX) Wc[(size_t)(n0 + nl) * KX + k0 + nc] = tile[nc * 66 + nl];
    }
    return;
  }
  if (blk < 380) {  // W2t / W3t
    int tt = blk - 348;
    const float* W = (tt < 16) ? g_w2 : g_w3;
    short* Wt = (tt < 16) ? W2t : W3t;
    tt &= 15;
    int k0 = (tt >> 2) * 64, n0 = (tt & 3) * 64;
    for (int p = 0; p < 16; p++) {
      int kl = p * 4 + r4;
      tile[kl * 66 + nc] = f2bf(W[(size_t)(k0 + kl) * 256 + n0 + nc]);
    }
    __syncthreads();
    for (int p = 0; p < 16; p++) {
      int nl = p * 4 + r4;
      Wt[(size_t)(n0 + nl) * 256 + k0 + nc] = tile[nc * 66 + nl];
    }
    return;
  }
  // zero rel: 8 blocks x 256 threads x 1 float4
  {
    int bb = blk - 380;
    ((f32x4*)rel)[bb * 256 + t] = (f32x4){0.f, 0.f, 0.f, 0.f};
  }
}

// ---------------- u/v GEMM: uv[m][0:256]=x@W_a, uv[m][256:512]=x@W_b + b1 ----------------
// one wave per block, 256 blocks (32 m-tiles x 8 n-tiles)

__global__ __launch_bounds__(64)
void uv_gemm(const short* __restrict__ xb, const short* __restrict__ Wab,
             const float* __restrict__ g_b1, float* __restrict__ uv) {
  const int m0 = blockIdx.x * 64;
  const int n0 = blockIdx.y * 64;
  const int lane = threadIdx.x;
  const int q = lane >> 4, l16 = lane & 15;

  f32x4 acc[4][4];
#pragma unroll
  for (int mt = 0; mt < 4; mt++)
#pragma unroll
    for (int nt = 0; nt < 4; nt++) acc[mt][nt] = (f32x4){0.f, 0.f, 0.f, 0.f};

  for (int k0 = 0; k0 < KX; k0 += 32) {
    frag8 a[4], bb[4];
#pragma unroll
    for (int mt = 0; mt < 4; mt++)
      a[mt] = *(const frag8*)(xb + (size_t)(m0 + mt * 16 + l16) * KX + k0 + q * 8);
#pragma unroll
    for (int nt = 0; nt < 4; nt++)
      bb[nt] = *(const frag8*)(Wab + (size_t)(n0 + nt * 16 + l16) * KX + k0 + q * 8);
#pragma unroll
    for (int mt = 0; mt < 4; mt++)
#pragma unroll
      for (int nt = 0; nt < 4; nt++)
        acc[mt][nt] = __builtin_amdgcn_mfma_f32_16x16x32_bf16(a[mt], bb[nt], acc[mt][nt], 0, 0, 0);
  }
#pragma unroll
  for (int nt = 0; nt < 4; nt++) {
    int col = n0 + nt * 16 + l16;
    float bias = (col >= 256) ? g_b1[col - 256] : 0.f;
#pragma unroll
    for (int mt = 0; mt < 4; mt++) {
      int m = m0 + mt * 16 + q * 4;
#pragma unroll
      for (int r = 0; r < 4; r++)
        uv[(size_t)(m + r) * 512 + col] = acc[mt][nt][r] + bias;
    }
  }
}

// ---------------- main fused relation kernel ----------------
// block = (b, i). One LDS union buffer, stride AS=296 shorts per row:
//   A view: row j = pair products, 288 elems at lds[j*AS]
//   H view: row r = h1/h2, 256 elems at lds[r*AS] (after barrier)

#define AS 296   // 592B row = 37*16B; row-to-row bank offset 148%32=20, 2-way max
#define LDS_SHORTS (64 * AS)  // 18944 shorts = 37888 B

__global__ __launch_bounds__(256, 3)
void relnet_main(const short* __restrict__ xb, const short* __restrict__ Wc,
                 const short* __restrict__ W2t, const short* __restrict__ W3t,
                 const float* __restrict__ uv, const float* __restrict__ g_b2,
                 const float* __restrict__ g_b3, float* __restrict__ rel) {
  __shared__ short lds[LDS_SHORTS];

  const int tid = threadIdx.x;
  const int bi = blockIdx.x;
  const int b = bi >> 6, i = bi & 63;
  const int lane = tid & 63, wave = tid >> 6;
  const int q = lane >> 4, l16 = lane & 15;
  const int n0 = wave * 64;
  const int rowbase = b * 64;
  const short* xi = xb + (size_t)(rowbase + i) * KX;

  f32x4 acc[4][4];
#pragma unroll
  for (int mt = 0; mt < 4; mt++)
#pragma unroll
    for (int nt = 0; nt < 4; nt++) acc[mt][nt] = (f32x4){0.f, 0.f, 0.f, 0.f};

  // ---- stage all pair products: 64 rows x 288 = 2304 frag8 chunks / 256 thr = 9 each
#pragma unroll
  for (int it = 0; it < 9; it++) {
    int idx = tid + it * 256;
    int j = idx / 36, k8 = (idx - j * 36) * 8;
    frag8 aj = *(const frag8*)(xb + (size_t)(rowbase + j) * KX + k8);
    frag8 ai = *(const frag8*)(xi + k8);
    frag8 r;
#pragma unroll
    for (int t = 0; t < 8; t++) r[t] = f2bf(bf2f(aj[t]) * bf2f(ai[t]));
    *(frag8*)(&lds[j * AS + k8]) = r;
  }
  __syncthreads();

  // ---- layer 1: 9 pipelined k-steps over A(LDS) x Wc(L2) ----
  {
    frag8 a0[4], b0[4], a1[4], b1[4];
#pragma unroll
    for (int mt = 0; mt < 4; mt++)
      a0[mt] = *(const frag8*)(&lds[(mt * 16 + l16) * AS + q * 8]);
#pragma unroll
    for (int nt = 0; nt < 4; nt++)
      b0[nt] = *(const frag8*)(Wc + (size_t)(n0 + nt * 16 + l16) * KX + q * 8);
#pragma unroll
    for (int ks = 0; ks < 9; ks++) {
      if (ks < 8) {
        int k1 = (ks + 1) * 32;
#pragma unroll
        for (int mt = 0; mt < 4; mt++)
          a1[mt] = *(const frag8*)(&lds[(mt * 16 + l16) * AS + k1 + q * 8]);
#pragma unroll
        for (int nt = 0; nt < 4; nt++)
          b1[nt] = *(const frag8*)(Wc + (size_t)(n0 + nt * 16 + l16) * KX + k1 + q * 8);
      }
#pragma unroll
      for (int mt = 0; mt < 4; mt++)
#pragma unroll
        for (int nt = 0; nt < 4; nt++)
          acc[mt][nt] = __builtin_amdgcn_mfma_f32_16x16x32_bf16(a0[mt], b0[nt], acc[mt][nt], 0, 0, 0);
#pragma unroll
      for (int mt = 0; mt < 4; mt++) a0[mt] = a1[mt];
#pragma unroll
      for (int nt = 0; nt < 4; nt++) b0[nt] = b1[nt];
    }
  }
  __syncthreads();  // all waves done reading A before H overwrites the union

  // ---- layer 1 epilogue: h1 = relu(acc + u[j] + v[i] + b1) -> H (bf16) ----
  {
    const float* ub = uv + (size_t)rowbase * 512;
    const float* vp = uv + (size_t)(rowbase + i) * 512 + 256;  // v + b1 already
#pragma unroll
    for (int nt = 0; nt < 4; nt++) {
      int col = n0 + nt * 16 + l16;
      float vv = vp[col];
#pragma unroll
      for (int mt = 0; mt < 4; mt++) {
        int jb = mt * 16 + q * 4;
#pragma unroll
        for (int r = 0; r < 4; r++) {
          float val = acc[mt][nt][r] + ub[(size_t)(jb + r) * 512 + col] + vv;
          lds[(jb + r) * AS + col] = f2bf(fmaxf(val, 0.f));
        }
        acc[mt][nt] = (f32x4){0.f, 0.f, 0.f, 0.f};
      }
    }
  }
  __syncthreads();

  // ---- layer 2: 8 pipelined k-steps, h1(LDS) x W2t(L2) ----
  {
    frag8 a0[4], b0[4], a1[4], b1[4];
#pragma unroll
    for (int mt = 0; mt < 4; mt++)
      a0[mt] = *(const frag8*)(&lds[(mt * 16 + l16) * AS + q * 8]);
#pragma unroll
    for (int nt = 0; nt < 4; nt++)
      b0[nt] = *(const frag8*)(W2t + (size_t)(n0 + nt * 16 + l16) * 256 + q * 8);
#pragma unroll
    for (int ks = 0; ks < 8; ks++) {
      if (ks < 7) {
        int k1 = (ks + 1) * 32;
#pragma unroll
        for (int mt = 0; mt < 4; mt++)
          a1[mt] = *(const frag8*)(&lds[(mt * 16 + l16) * AS + k1 + q * 8]);
#pragma unroll
        for (int nt = 0; nt < 4; nt++)
          b1[nt] = *(const frag8*)(W2t + (size_t)(n0 + nt * 16 + l16) * 256 + k1 + q * 8);
      }
#pragma unroll
      for (int mt = 0; mt < 4; mt++)
#pragma unroll
        for (int nt = 0; nt < 4; nt++)
          acc[mt][nt] = __builtin_amdgcn_mfma_f32_16x16x32_bf16(a0[mt], b0[nt], acc[mt][nt], 0, 0, 0);
#pragma unroll
      for (int mt = 0; mt < 4; mt++) a0[mt] = a1[mt];
#pragma unroll
      for (int nt = 0; nt < 4; nt++) b0[nt] = b1[nt];
    }
  }
  __syncthreads();  // all waves done READING h1 before overwriting with h2
#pragma unroll
  for (int nt = 0; nt < 4; nt++) {
    int col = n0 + nt * 16 + l16;
    float b2 = g_b2[col];
#pragma unroll
    for (int mt = 0; mt < 4; mt++) {
      int jb = mt * 16 + q * 4;
#pragma unroll
      for (int r = 0; r < 4; r++)
        lds[(jb + r) * AS + col] = f2bf(fmaxf(acc[mt][nt][r] + b2, 0.f));
      acc[mt][nt] = (f32x4){0.f, 0.f, 0.f, 0.f};
    }
  }
  __syncthreads();

  // ---- layer 3: 8 pipelined k-steps, h2(LDS) x W3t(L2); reduce over j; atomic ----
  {
    frag8 a0[4], b0[4], a1[4], b1[4];
#pragma unroll
    for (int mt = 0; mt < 4; mt++)
      a0[mt] = *(const frag8*)(&lds[(mt * 16 + l16) * AS + q * 8]);
#pragma unroll
    for (int nt = 0; nt < 4; nt++)
      b0[nt] = *(const frag8*)(W3t + (size_t)(n0 + nt * 16 + l16) * 256 + q * 8);
#pragma unroll
    for (int ks = 0; ks < 8; ks++) {
      if (ks < 7) {
        int k1 = (ks + 1) * 32;
#pragma unroll
        for (int mt = 0; mt < 4; mt++)
          a1[mt] = *(const frag8*)(&lds[(mt * 16 + l16) * AS + k1 + q * 8]);
#pragma unroll
        for (int nt = 0; nt < 4; nt++)
          b1[nt] = *(const frag8*)(W3t + (size_t)(n0 + nt * 16 + l16) * 256 + k1 + q * 8);
      }
#pragma unroll
      for (int mt = 0; mt < 4; mt++)
#pragma unroll
        for (int nt = 0; nt < 4; nt++)
          acc[mt][nt] = __builtin_amdgcn_mfma_f32_16x16x32_bf16(a0[mt], b0[nt], acc[mt][nt], 0, 0, 0);
#pragma unroll
      for (int mt = 0; mt < 4; mt++) a0[mt] = a1[mt];
#pragma unroll
      for (int nt = 0; nt < 4; nt++) b0[nt] = b1[nt];
    }
  }
#pragma unroll
  for (int nt = 0; nt < 4; nt++) {
    int col = n0 + nt * 16 + l16;
    float b3 = g_b3[col];
    float s = 0.f;
#pragma unroll
    for (int mt = 0; mt < 4; mt++)
#pragma unroll
      for (int r = 0; r < 4; r++)
        s += fmaxf(acc[mt][nt][r] + b3, 0.f);
    s += __shfl_xor(s, 16, 64);
    s += __shfl_xor(s, 32, 64);
    if (q == 0) atomicAdd(&rel[b * 256 + col], s);
  }
}

// ---------------- f-network (fp32, exact) ----------------
__global__ __launch_bounds__(256)
void fnet(const float* __restrict__ rel, const float* __restrict__ f_w1,
          const float* __restrict__ f_b1, const float* __restrict__ f_w2,
          const float* __restrict__ f_b2, const float* __restrict__ f_w3,
          const float* __restrict__ f_b3, float* __restrict__ out) {
  int b = blockIdx.x, t = threadIdx.x;
  __shared__ float y0[256], y1[256], y2[256];
  y0[t] = rel[b * 256 + t];
  __syncthreads();
  float s = f_b1[t];
#pragma unroll 8
  for (int k = 0; k < 256; k++) s += y0[k] * f_w1[k * 256 + t];
  y1[t] = fmaxf(s, 0.f);
  __syncthreads();
  s = f_b2[t];
#pragma unroll 8
  for (int k = 0; k < 256; k++) s += y1[k] * f_w2[k * 256 + t];
  y2[t] = fmaxf(s, 0.f);
  __syncthreads();
  if (t < 10) {
    float s2 = f_b3[t];
#pragma unroll 8
    for (int k = 0; k < 256; k++) s2 += y2[k] * f_w3[k * 10 + t];
    out[b * 10 + t] = s2;
  }
}

// ---------------- launch ----------------
extern "C" void kernel_launch(void* const* d_in, const int* in_sizes, int n_in,
                              void* d_out, int out_size, void* d_ws, size_t ws_size,
                              hipStream_t stream) {
  const float* sent  = (const float*)d_in[0];
  const float* coord = (const float*)d_in[1];
  const float* g_w1  = (const float*)d_in[2];
  const float* g_b1  = (const float*)d_in[3];
  const float* g_w2  = (const float*)d_in[4];
  const float* g_b2  = (const float*)d_in[5];
  const float* g_w3  = (const float*)d_in[6];
  const float* g_b3  = (const float*)d_in[7];
  const float* f_w1  = (const float*)d_in[8];
  const float* f_b1  = (const float*)d_in[9];
  const float* f_w2  = (const float*)d_in[10];
  const float* f_b2  = (const float*)d_in[11];
  const float* f_w3  = (const float*)d_in[12];
  const float* f_b3  = (const float*)d_in[13];
  float* out = (float*)d_out;

  char* ws = (char*)d_ws;
  size_t off = 0;
  auto alloc = [&](size_t bytes) {
    char* p = ws + off;
    off += (bytes + 255) & ~(size_t)255;
    return p;
  };
  short* xb  = (short*)alloc((size_t)2048 * KX * 2);
  short* Wab = (short*)alloc((size_t)512 * KX * 2);
  short* Wc  = (short*)alloc((size_t)256 * KX * 2);
  short* W2t = (short*)alloc((size_t)256 * 256 * 2);
  short* W3t = (short*)alloc((size_t)256 * 256 * 2);
  float* uv  = (float*)alloc((size_t)2048 * 512 * 4);
  float* rel = (float*)alloc((size_t)32 * 256 * 4);

  prep<<<388, 256, 0, stream>>>(sent, coord, g_w1, g_w2, g_w3, xb, Wab, Wc, W2t, W3t, rel);
  uv_gemm<<<dim3(32, 8), 64, 0, stream>>>(xb, Wab, g_b1, uv);
  relnet_main<<<2048, 256, 0, stream>>>(xb, Wc, W2t, W3t, uv, g_b2, g_b3, rel);
  fnet<<<32, 256, 0, stream>>>(rel, f_w1, f_b1, f_w2, f_b2, f_w3, f_b3, out);
}

// Round 5
// 184.602 us; speedup vs baseline: 1.3348x; 1.1609x over previous
//
#include <hip/hip_runtime.h>
#include <hip/hip_bf16.h>

// RelationsNetwork on MI355X.
// Decomposition: h1 = relu(u[j] + v[i] + (x_i*x_j)@W_c + b1), u=x@W_a, v=x@W_b
// where g_w1 = [W_a; W_b; W_c] (rows 0:258, 258:516, 516:774).
// Round-5 structure: one block per (b, i-pair) -> M=128 pair-rows per block
// (1024 blocks). Halves the per-block-amortized L2 weight streaming
// (round-4: 8192 waves x ~102KB = 1.08 GB ~ 30 us at L2 ceiling) and doubles
// MFMA per weight byte. MFMA shape 32x32x16 (2382 vs 2075 TF; 4x fewer instrs).
// acc = 4mt x 2nt x 16f = 128 AGPR -> __launch_bounds__(256,2) (256-reg cap,
// no spill; (256,4)'s 128-cap spilled 85MB in round 2).
// LDS: layer-1 pair products staged in two K=144 halves (128 x stride152 =
// 38912 B, rows tile banks); H = 128x256 bf16 stride-256 with XOR chunk
// swizzle c^(m&7) (unswizzled stride-256 would put every row on banks 0-3).
// Union 65536 B. j,i-reduction in-register; atomicAdd into rel[b,h].

typedef __attribute__((ext_vector_type(4))) float f32x4;
typedef __attribute__((ext_vector_type(16))) float f32x16;
typedef __attribute__((ext_vector_type(8))) short frag8;  // 8 bf16 = 4 VGPR

__device__ __forceinline__ float bf2f(short s) {
  return __uint_as_float(((unsigned)(unsigned short)s) << 16);
}
__device__ __forceinline__ short f2bf(float f) {
  unsigned u = __float_as_uint(f);
  return (short)((u + 0x7fffu + ((u >> 16) & 1u)) >> 16);
}

#define KX 288   // padded 258 -> 288 (two K-halves of 144)

// ---------------- merged prep kernel ----------------
// regions by blockIdx.x:
//   [0,288)    build_x:  xb[(b*64+s)*288+k] = bf16(x[b,s,k])
//   [288,328)  Wab:  [n][k] n<256 -> W_a col n ; n>=256 -> W_b col n-256
//   [328,348)  Wc:   [n][k] = g_w1[516+k][n]
//   [348,364)  W2t:  [n][k] = g_w2[k][n]
//   [364,380)  W3t:  [n][k] = g_w3[k][n]
//   [380,388)  zero rel
__global__ __launch_bounds__(256)
void prep(const float* __restrict__ sent, const float* __restrict__ coord,
          const float* __restrict__ g_w1, const float* __restrict__ g_w2,
          const float* __restrict__ g_w3,
          short* __restrict__ xb, short* __restrict__ Wab, short* __restrict__ Wc,
          short* __restrict__ W2t, short* __restrict__ W3t, float* __restrict__ rel) {
  __shared__ short tile[64 * 66];  // odd-dword stride: conflict-free transpose
  const int blk = blockIdx.x, t = threadIdx.x;

  if (blk < 288) {
    long idx0 = ((long)blk * 256 + t) * 8;
#pragma unroll
    for (int e = 0; e < 8; e++) {
      long idx = idx0 + e;
      int row = (int)(idx / KX), k = (int)(idx - (long)row * KX);
      float v = 0.f;
      if (k < 256)      v = sent[(size_t)row * 256 + k];
      else if (k < 258) v = coord[row * 2 + (k - 256)];
      xb[idx] = f2bf(v);
    }
    return;
  }

  const int nc = t & 63, r4 = t >> 6;  // read: 4 rows x 64 cols per pass
  if (blk < 328) {  // Wab
    int tt = blk - 288, kt = tt >> 3, nt = tt & 7;
    int k0 = kt * 64, n0 = nt * 64;
    for (int p = 0; p < 16; p++) {
      int kl = p * 4 + r4, k = k0 + kl, n = n0 + nc;
      float v = 0.f;
      if (k < 258) {
        int row = (n < 256) ? k : 258 + k;
        int col = (n < 256) ? n : n - 256;
        v = g_w1[(size_t)row * 256 + col];
      }
      tile[kl * 66 + nc] = f2bf(v);
    }
    __syncthreads();
    for (int p = 0; p < 16; p++) {
      int nl = p * 4 + r4;
      if (k0 + nc < KX) Wab[(size_t)(n0 + nl) * KX + k0 + nc] = tile[nc * 66 + nl];
    }
    return;
  }
  if (blk < 348) {  // Wc
    int tt = blk - 328, kt = tt >> 2, nt = tt & 3;
    int k0 = kt * 64, n0 = nt * 64;
    for (int p = 0; p < 16; p++) {
      int kl = p * 4 + r4, k = k0 + kl;
      float v = (k < 258) ? g_w1[(size_t)(516 + k) * 256 + n0 + nc] : 0.f;
      tile[kl * 66 + nc] = f2bf(v);
    }
    __syncthreads();
    for (int p = 0; p < 16; p++) {
      int nl = p * 4 + r4;
      if (k0 + nc < KX) Wc[(size_t)(n0 + nl) * KX + k0 + nc] = tile[nc * 66 + nl];
    }
    return;
  }
  if (blk < 380) {  // W2t / W3t
    int tt = blk - 348;
    const float* W = (tt < 16) ? g_w2 : g_w3;
    short* Wt = (tt < 16) ? W2t : W3t;
    tt &= 15;
    int k0 = (tt >> 2) * 64, n0 = (tt & 3) * 64;
    for (int p = 0; p < 16; p++) {
      int kl = p * 4 + r4;
      tile[kl * 66 + nc] = f2bf(W[(size_t)(k0 + kl) * 256 + n0 + nc]);
    }
    __syncthreads();
    for (int p = 0; p < 16; p++) {
      int nl = p * 4 + r4;
      Wt[(size_t)(n0 + nl) * 256 + k0 + nc] = tile[nc * 66 + nl];
    }
    return;
  }
  // zero rel: 8 blocks x 256 threads x 1 float4
  {
    int bb = blk - 380;
    ((f32x4*)rel)[bb * 256 + t] = (f32x4){0.f, 0.f, 0.f, 0.f};
  }
}

// ---------------- u/v GEMM: uv[m][0:256]=x@W_a, uv[m][256:512]=x@W_b + b1 ----------------
// one wave per block, 256 blocks (32 m-tiles x 8 n-tiles); 16x16x32 (known-good)

__global__ __launch_bounds__(64)
void uv_gemm(const short* __restrict__ xb, const short* __restrict__ Wab,
             const float* __restrict__ g_b1, float* __restrict__ uv) {
  const int m0 = blockIdx.x * 64;
  const int n0 = blockIdx.y * 64;
  const int lane = threadIdx.x;
  const int q = lane >> 4, l16 = lane & 15;

  f32x4 acc[4][4];
#pragma unroll
  for (int mt = 0; mt < 4; mt++)
#pragma unroll
    for (int nt = 0; nt < 4; nt++) acc[mt][nt] = (f32x4){0.f, 0.f, 0.f, 0.f};

  for (int k0 = 0; k0 < KX; k0 += 32) {
    frag8 a[4], bb[4];
#pragma unroll
    for (int mt = 0; mt < 4; mt++)
      a[mt] = *(const frag8*)(xb + (size_t)(m0 + mt * 16 + l16) * KX + k0 + q * 8);
#pragma unroll
    for (int nt = 0; nt < 4; nt++)
      bb[nt] = *(const frag8*)(Wab + (size_t)(n0 + nt * 16 + l16) * KX + k0 + q * 8);
#pragma unroll
    for (int mt = 0; mt < 4; mt++)
#pragma unroll
      for (int nt = 0; nt < 4; nt++)
        acc[mt][nt] = __builtin_amdgcn_mfma_f32_16x16x32_bf16(a[mt], bb[nt], acc[mt][nt], 0, 0, 0);
  }
#pragma unroll
  for (int nt = 0; nt < 4; nt++) {
    int col = n0 + nt * 16 + l16;
    float bias = (col >= 256) ? g_b1[col - 256] : 0.f;
#pragma unroll
    for (int mt = 0; mt < 4; mt++) {
      int m = m0 + mt * 16 + q * 4;
#pragma unroll
      for (int r = 0; r < 4; r++)
        uv[(size_t)(m + r) * 512 + col] = acc[mt][nt][r] + bias;
    }
  }
}

// ---------------- main fused relation kernel ----------------
// block = (b, ipair): rows m in [0,128): i = i0 + (m>>6), j = m&63.
// LDS union (65536 B):
//   A view (layer-1 staging, per K-half): row m at lds[m*152], 144 elems
//   H view (h1/h2): row m at lds[m*256], 256 elems, chunk swizzle c^(m&7)

#define ASH 152        // 304B row = 19*16B; 76 dwords % 32 = 12 -> rows 0..7 tile banks
#define LDS_SHORTS 32768  // 65536 B (H view = exactly 128*256)

__global__ __launch_bounds__(256, 2)
void relnet_main(const short* __restrict__ xb, const short* __restrict__ Wc,
                 const short* __restrict__ W2t, const short* __restrict__ W3t,
                 const float* __restrict__ uv, const float* __restrict__ g_b2,
                 const float* __restrict__ g_b3, float* __restrict__ rel) {
  __shared__ short lds[LDS_SHORTS];

  const int tid = threadIdx.x;
  const int bi = blockIdx.x;
  const int b = bi >> 5, ip = bi & 31;
  const int i0 = ip * 2;
  const int lane = tid & 63, wave = tid >> 6;
  const int l32 = lane & 31, half = lane >> 5;
  const int n0 = wave * 64;
  const int rowbase = b * 64;

  f32x16 acc[4][2];
#pragma unroll
  for (int mt = 0; mt < 4; mt++)
#pragma unroll
    for (int nt = 0; nt < 2; nt++)
#pragma unroll
      for (int r = 0; r < 16; r++) acc[mt][nt][r] = 0.f;

  // ---- layer 1: two K-halves of 144, staged then 9 pipelined 32x32x16 steps ----
#pragma unroll
  for (int h = 0; h < 2; h++) {
    const int kbase = h * 144;
    // stage: 128 rows x 18 chunks = 2304 / 256 thr = 9 chunks each
#pragma unroll
    for (int it = 0; it < 9; it++) {
      int idx = tid + it * 256;
      int j = idx / 18, c = idx - j * 18;
      int k = kbase + c * 8;
      int jj = j & 63, iL = j >> 6;
      frag8 aj = *(const frag8*)(xb + (size_t)(rowbase + jj) * KX + k);
      frag8 ai = *(const frag8*)(xb + (size_t)(rowbase + i0 + iL) * KX + k);
      frag8 r;
#pragma unroll
      for (int t = 0; t < 8; t++) r[t] = f2bf(bf2f(aj[t]) * bf2f(ai[t]));
      *(frag8*)(&lds[j * ASH + c * 8]) = r;
    }
    __syncthreads();

    {
      frag8 a0[4], b0[2], a1[4], b1[2];
#pragma unroll
      for (int mt = 0; mt < 4; mt++)
        a0[mt] = *(const frag8*)(&lds[(mt * 32 + l32) * ASH + half * 8]);
#pragma unroll
      for (int nt = 0; nt < 2; nt++)
        b0[nt] = *(const frag8*)(Wc + (size_t)(n0 + nt * 32 + l32) * KX + kbase + half * 8);
#pragma unroll
      for (int ks = 0; ks < 9; ks++) {
        if (ks < 8) {
          int k1 = (ks + 1) * 16 + half * 8;
#pragma unroll
          for (int mt = 0; mt < 4; mt++)
            a1[mt] = *(const frag8*)(&lds[(mt * 32 + l32) * ASH + k1]);
#pragma unroll
          for (int nt = 0; nt < 2; nt++)
            b1[nt] = *(const frag8*)(Wc + (size_t)(n0 + nt * 32 + l32) * KX + kbase + k1);
        }
#pragma unroll
        for (int mt = 0; mt < 4; mt++)
#pragma unroll
          for (int nt = 0; nt < 2; nt++)
            acc[mt][nt] = __builtin_amdgcn_mfma_f32_32x32x16_bf16(a0[mt], b0[nt], acc[mt][nt], 0, 0, 0);
#pragma unroll
        for (int mt = 0; mt < 4; mt++) a0[mt] = a1[mt];
#pragma unroll
        for (int nt = 0; nt < 2; nt++) b0[nt] = b1[nt];
      }
    }
    __syncthreads();  // staging (h=1) / H-epilogue must not overwrite live A
  }

  // ---- layer 1 epilogue: h1 = relu(acc + u[j] + v[i] + b1) -> H (swizzled) ----
  {
    const float* ub = uv + (size_t)rowbase * 512;
    const float* v0p = uv + (size_t)(rowbase + i0) * 512 + 256;      // v(i0) + b1
    const float* v1p = uv + (size_t)(rowbase + i0 + 1) * 512 + 256;  // v(i1) + b1
#pragma unroll
    for (int nt = 0; nt < 2; nt++) {
      int col = n0 + nt * 32 + l32;
      int cb = (n0 + nt * 32) >> 3;
      float vv0 = v0p[col], vv1 = v1p[col];
#pragma unroll
      for (int mt = 0; mt < 4; mt++) {
        float vv = (mt < 2) ? vv0 : vv1;
#pragma unroll
        for (int r = 0; r < 16; r++) {
          int rowbits = (r & 3) + 8 * (r >> 2) + 4 * half;
          int jm = (mt & 1) * 32 + rowbits;            // j index within batch
          int m = mt * 32 + rowbits;                   // H row
          float val = acc[mt][nt][r] + ub[(size_t)jm * 512 + col] + vv;
          int sw = (r & 3) + 4 * half;                 // = m & 7
          lds[m * 256 + (((cb + (l32 >> 3)) ^ sw) << 3) + (l32 & 7)] = f2bf(fmaxf(val, 0.f));
        }
#pragma unroll
        for (int r = 0; r < 16; r++) acc[mt][nt][r] = 0.f;
      }
    }
  }
  __syncthreads();

  // ---- layer 2: h2 = relu(h1 @ W2 + b2), 16 pipelined steps ----
  {
    const int swr = l32 & 7;  // A-row swizzle key (uniform across mt)
    frag8 a0[4], b0[2], a1[4], b1[2];
#pragma unroll
    for (int mt = 0; mt < 4; mt++)
      a0[mt] = *(const frag8*)(&lds[(mt * 32 + l32) * 256 + ((half ^ swr) << 3)]);
#pragma unroll
    for (int nt = 0; nt < 2; nt++)
      b0[nt] = *(const frag8*)(W2t + (size_t)(n0 + nt * 32 + l32) * 256 + half * 8);
#pragma unroll
    for (int ks = 0; ks < 16; ks++) {
      if (ks < 15) {
        int c1 = ((2 * (ks + 1) + half) ^ swr) << 3;
        int k1 = (ks + 1) * 16 + half * 8;
#pragma unroll
        for (int mt = 0; mt < 4; mt++)
          a1[mt] = *(const frag8*)(&lds[(mt * 32 + l32) * 256 + c1]);
#pragma unroll
        for (int nt = 0; nt < 2; nt++)
          b1[nt] = *(const frag8*)(W2t + (size_t)(n0 + nt * 32 + l32) * 256 + k1);
      }
#pragma unroll
      for (int mt = 0; mt < 4; mt++)
#pragma unroll
        for (int nt = 0; nt < 2; nt++)
          acc[mt][nt] = __builtin_amdgcn_mfma_f32_32x32x16_bf16(a0[mt], b0[nt], acc[mt][nt], 0, 0, 0);
#pragma unroll
      for (int mt = 0; mt < 4; mt++) a0[mt] = a1[mt];
#pragma unroll
      for (int nt = 0; nt < 2; nt++) b0[nt] = b1[nt];
    }
  }
  __syncthreads();  // all reads of h1 done before h2 overwrites
#pragma unroll
  for (int nt = 0; nt < 2; nt++) {
    int col = n0 + nt * 32 + l32;
    int cb = (n0 + nt * 32) >> 3;
    float b2 = g_b2[col];
#pragma unroll
    for (int mt = 0; mt < 4; mt++) {
#pragma unroll
      for (int r = 0; r < 16; r++) {
        int rowbits = (r & 3) + 8 * (r >> 2) + 4 * half;
        int m = mt * 32 + rowbits;
        int sw = (r & 3) + 4 * half;
        lds[m * 256 + (((cb + (l32 >> 3)) ^ sw) << 3) + (l32 & 7)] =
            f2bf(fmaxf(acc[mt][nt][r] + b2, 0.f));
      }
#pragma unroll
      for (int r = 0; r < 16; r++) acc[mt][nt][r] = 0.f;
    }
  }
  __syncthreads();

  // ---- layer 3: h3 = relu(h2 @ W3 + b3); reduce over (i,j); atomic into rel ----
  {
    const int swr = l32 & 7;
    frag8 a0[4], b0[2], a1[4], b1[2];
#pragma unroll
    for (int mt = 0; mt < 4; mt++)
      a0[mt] = *(const frag8*)(&lds[(mt * 32 + l32) * 256 + ((half ^ swr) << 3)]);
#pragma unroll
    for (int nt = 0; nt < 2; nt++)
      b0[nt] = *(const frag8*)(W3t + (size_t)(n0 + nt * 32 + l32) * 256 + half * 8);
#pragma unroll
    for (int ks = 0; ks < 16; ks++) {
      if (ks < 15) {
        int c1 = ((2 * (ks + 1) + half) ^ swr) << 3;
        int k1 = (ks + 1) * 16 + half * 8;
#pragma unroll
        for (int mt = 0; mt < 4; mt++)
          a1[mt] = *(const frag8*)(&lds[(mt * 32 + l32) * 256 + c1]);
#pragma unroll
        for (int nt = 0; nt < 2; nt++)
          b1[nt] = *(const frag8*)(W3t + (size_t)(n0 + nt * 32 + l32) * 256 + k1);
      }
#pragma unroll
      for (int mt = 0; mt < 4; mt++)
#pragma unroll
        for (int nt = 0; nt < 2; nt++)
          acc[mt][nt] = __builtin_amdgcn_mfma_f32_32x32x16_bf16(a0[mt], b0[nt], acc[mt][nt], 0, 0, 0);
#pragma unroll
      for (int mt = 0; mt < 4; mt++) a0[mt] = a1[mt];
#pragma unroll
      for (int nt = 0; nt < 2; nt++) b0[nt] = b1[nt];
    }
  }
#pragma unroll
  for (int nt = 0; nt < 2; nt++) {
    int col = n0 + nt * 32 + l32;
    float b3 = g_b3[col];
    float s = 0.f;
#pragma unroll
    for (int mt = 0; mt < 4; mt++)
#pragma unroll
      for (int r = 0; r < 16; r++)
        s += fmaxf(acc[mt][nt][r] + b3, 0.f);
    s += __shfl_xor(s, 32, 64);
    if (half == 0) atomicAdd(&rel[b * 256 + col], s);
  }
}

// ---------------- f-network (fp32, exact) ----------------
__global__ __launch_bounds__(256)
void fnet(const float* __restrict__ rel, const float* __restrict__ f_w1,
          const float* __restrict__ f_b1, const float* __restrict__ f_w2,
          const float* __restrict__ f_b2, const float* __restrict__ f_w3,
          const float* __restrict__ f_b3, float* __restrict__ out) {
  int b = blockIdx.x, t = threadIdx.x;
  __shared__ float y0[256], y1[256], y2[256];
  y0[t] = rel[b * 256 + t];
  __syncthreads();
  float s = f_b1[t];
#pragma unroll 8
  for (int k = 0; k < 256; k++) s += y0[k] * f_w1[k * 256 + t];
  y1[t] = fmaxf(s, 0.f);
  __syncthreads();
  s = f_b2[t];
#pragma unroll 8
  for (int k = 0; k < 256; k++) s += y1[k] * f_w2[k * 256 + t];
  y2[t] = fmaxf(s, 0.f);
  __syncthreads();
  if (t < 10) {
    float s2 = f_b3[t];
#pragma unroll 8
    for (int k = 0; k < 256; k++) s2 += y2[k] * f_w3[k * 10 + t];
    out[b * 10 + t] = s2;
  }
}

// ---------------- launch ----------------
extern "C" void kernel_launch(void* const* d_in, const int* in_sizes, int n_in,
                              void* d_out, int out_size, void* d_ws, size_t ws_size,
                              hipStream_t stream) {
  const float* sent  = (const float*)d_in[0];
  const float* coord = (const float*)d_in[1];
  const float* g_w1  = (const float*)d_in[2];
  const float* g_b1  = (const float*)d_in[3];
  const float* g_w2  = (const float*)d_in[4];
  const float* g_b2  = (const float*)d_in[5];
  const float* g_w3  = (const float*)d_in[6];
  const float* g_b3  = (const float*)d_in[7];
  const float* f_w1  = (const float*)d_in[8];
  const float* f_b1  = (const float*)d_in[9];
  const float* f_w2  = (const float*)d_in[10];
  const float* f_b2  = (const float*)d_in[11];
  const float* f_w3  = (const float*)d_in[12];
  const float* f_b3  = (const float*)d_in[13];
  float* out = (float*)d_out;

  char* ws = (char*)d_ws;
  size_t off = 0;
  auto alloc = [&](size_t bytes) {
    char* p = ws + off;
    off += (bytes + 255) & ~(size_t)255;
    return p;
  };
  short* xb  = (short*)alloc((size_t)2048 * KX * 2);
  short* Wab = (short*)alloc((size_t)512 * KX * 2);
  short* Wc  = (short*)alloc((size_t)256 * KX * 2);
  short* W2t = (short*)alloc((size_t)256 * 256 * 2);
  short* W3t = (short*)alloc((size_t)256 * 256 * 2);
  float* uv  = (float*)alloc((size_t)2048 * 512 * 4);
  float* rel = (float*)alloc((size_t)32 * 256 * 4);

  prep<<<388, 256, 0, stream>>>(sent, coord, g_w1, g_w2, g_w3, xb, Wab, Wc, W2t, W3t, rel);
  uv_gemm<<<dim3(32, 8), 64, 0, stream>>>(xb, Wab, g_b1, uv);
  relnet_main<<<1024, 256, 0, stream>>>(xb, Wc, W2t, W3t, uv, g_b2, g_b3, rel);
  fnet<<<32, 256, 0, stream>>>(rel, f_w1, f_b1, f_w2, f_b2, f_w3, f_b3, out);
}